// Round 12
// baseline (167.140 us; speedup 1.0000x reference)
//
#include <hip/hip_runtime.h>

// Problem constants (fixed by reference setup_inputs)
#define NB 8192      // rows of X and Y
#define DD 512       // feature dim
#define INV_T 20.609929155556618f   // (float)(log2(e)/0.07)

typedef short bf16x8 __attribute__((ext_vector_type(8)));  // 8 bf16 in 4 VGPRs
typedef float f32x4  __attribute__((ext_vector_type(4)));

// round-to-nearest-even fp32 -> bf16
__device__ static inline unsigned short f2bf(float f) {
  unsigned int u = __float_as_uint(f);
  u += 0x7fff + ((u >> 16) & 1);
  return (unsigned short)(u >> 16);
}

// async global->LDS, 16B per lane; lds base wave-uniform, HW adds lane*16
__device__ static inline void async16(const void* lds, const void* g) {
  __builtin_amdgcn_global_load_lds(
      (const __attribute__((address_space(1))) unsigned int*)g,
      (__attribute__((address_space(3))) unsigned int*)lds, 16, 0, 0);
}

// -------- kernel 1: fused L2-normalize (fp32->bf16) + diagonal Sv --------
__global__ __launch_bounds__(256) void norm_kernel2(
    const float* __restrict__ X, const float* __restrict__ Y,
    unsigned short* __restrict__ Xnb, unsigned short* __restrict__ Ynb,
    float* __restrict__ Sv) {
  const int wv   = threadIdx.x >> 6;
  const int lane = threadIdx.x & 63;
  const int row  = blockIdx.x * 4 + wv;
  const float4* x4 = (const float4*)(X + (size_t)row * DD);
  const float4* y4 = (const float4*)(Y + (size_t)row * DD);
  float4 xa = x4[lane], xb = x4[lane + 64];
  float4 ya = y4[lane], yb = y4[lane + 64];
  float xs[8] = {xa.x, xa.y, xa.z, xa.w, xb.x, xb.y, xb.z, xb.w};
  float ys[8] = {ya.x, ya.y, ya.z, ya.w, yb.x, yb.y, yb.z, yb.w};
  float ssx = 0.f, ssy = 0.f, sxy = 0.f;
#pragma unroll
  for (int k = 0; k < 8; ++k) {
    ssx += xs[k] * xs[k];
    ssy += ys[k] * ys[k];
    sxy += xs[k] * ys[k];
  }
#pragma unroll
  for (int m = 1; m < 64; m <<= 1) {
    ssx += __shfl_xor(ssx, m);
    ssy += __shfl_xor(ssy, m);
    sxy += __shfl_xor(sxy, m);
  }
  const float rnx = 1.0f / sqrtf(ssx);
  const float rny = 1.0f / sqrtf(ssy);
  unsigned short ox[8], oy[8];
#pragma unroll
  for (int k = 0; k < 8; ++k) {
    ox[k] = f2bf(xs[k] * rnx);
    oy[k] = f2bf(ys[k] * rny);
  }
  *(uint2*)(Xnb + (size_t)row * DD + lane * 4)       = *(const uint2*)&ox[0];
  *(uint2*)(Xnb + (size_t)row * DD + 256 + lane * 4) = *(const uint2*)&ox[4];
  *(uint2*)(Ynb + (size_t)row * DD + lane * 4)       = *(const uint2*)&oy[0];
  *(uint2*)(Ynb + (size_t)row * DD + 256 + lane * 4) = *(const uint2*)&oy[4];
  if (lane == 0) Sv[row] = sxy * rnx * rny * INV_T - INV_T;
}

// -------- kernel 2: 256x256 tile, balanced 4-phase pipeline ----------------
// Per K-tile t (cur = buf[t&1], other = buf[1-(t&1)], t+2 staged into cur):
//  Ph0: read a1<-cur (8)                  | Q(0,0)[a0,b01] | lgkm bar
//  Ph1: read b23<-cur (4) | stage A(t+2)  | Q(1,0)[a1,b01] | lgkm vmcnt(4) bar
//  Ph2: read b01<-other(4)| stage B(t+2)  | Q(0,1)[a0,b23] | lgkm bar
//  Ph3: Q(1,1)[a1,b23] | read a0<-other (8, after last a0 use) | lgkm bar
// Reads spread 8/4/4/8, stages 0/4/4/0 -> every segment overlaps LDS & MFMA.
// vmcnt(4) at Ph1: outstanding = A(t+1),B(t+1),A(t+2)x4 -> waits t+1 landed.

#define STAGE_A(BUF, T) do {                                                   \
  _Pragma("unroll") for (int h_ = 0; h_ < 2; ++h_) {                           \
    async16(sT + (BUF) + h_ * 16384 + wv * 1024,                               \
            Ab + h_ * 131072 + (T) * 128 + g0);                                \
    async16(sT + (BUF) + h_ * 16384 + 8192 + wv * 1024,                        \
            Ab + h_ * 131072 + (T) * 128 + g1);                                \
  } } while (0)

#define STAGE_B(BUF, T) do {                                                   \
  _Pragma("unroll") for (int h_ = 0; h_ < 2; ++h_) {                           \
    async16(sT + (BUF) + 32768 + h_ * 16384 + wv * 1024,                       \
            Bb + h_ * 131072 + (T) * 128 + g0);                                \
    async16(sT + (BUF) + 32768 + h_ * 16384 + 8192 + wv * 1024,                \
            Bb + h_ * 131072 + (T) * 128 + g1);                                \
  } } while (0)

#define READ_A8(DST, BUF, MH) do {                                             \
  _Pragma("unroll") for (int ks_ = 0; ks_ < 2; ++ks_)                          \
  _Pragma("unroll") for (int i_ = 0; i_ < 4; ++i_)                             \
    DST[ks_][i_] = *(const bf16x8*)(sT + (BUF) + raB[ks_]                      \
                                    + (MH) * 8192 + i_ * 2048);                \
  } while (0)

#define READ_B4(DST, BUF, J0) do {                                             \
  _Pragma("unroll") for (int ks_ = 0; ks_ < 2; ++ks_)                          \
  _Pragma("unroll") for (int j_ = 0; j_ < 2; ++j_)                             \
    DST[ks_][j_] = *(const bf16x8*)(sT + (BUF) + rbB[ks_]                      \
                                    + ((J0) + j_) * 2048);                     \
  } while (0)

#define QUADX(MH, NH, A_, B_) do {                                             \
  __builtin_amdgcn_s_setprio(1);                                               \
  _Pragma("unroll") for (int ks_ = 0; ks_ < 2; ++ks_)                          \
  _Pragma("unroll") for (int i_ = 0; i_ < 4; ++i_)                             \
  _Pragma("unroll") for (int j_ = 0; j_ < 2; ++j_)                             \
    acc[(MH) * 4 + i_][(NH) * 2 + j_] =                                        \
      __builtin_amdgcn_mfma_f32_16x16x32_bf16(                                 \
        A_[ks_][i_], B_[ks_][j_],                                              \
        acc[(MH) * 4 + i_][(NH) * 2 + j_], 0, 0, 0);                           \
  __builtin_amdgcn_s_setprio(0);                                               \
  } while (0)

#define PHASE_END_LGKM() do {                                                  \
  asm volatile("s_waitcnt lgkmcnt(0)" ::: "memory");                           \
  __builtin_amdgcn_s_barrier();                                                \
  __builtin_amdgcn_sched_barrier(0);                                           \
  } while (0)

__global__ __launch_bounds__(512, 1) void gemm_kernel(
    const unsigned short* __restrict__ Xnb, const unsigned short* __restrict__ Ynb,
    float* __restrict__ rowp, float* __restrict__ colp) {
  extern __shared__ __align__(16) char sT[];

  const int tid  = threadIdx.x;
  const int wv   = tid >> 6;
  const int lane = tid & 63;
  const int l16  = lane & 15;
  const int lg   = lane >> 4;
  const int wr   = wv >> 2, wc = wv & 3;      // 2 x 4 wave grid

  // T1: XCD cluster swizzle (proven r8).
  const int bid = blockIdx.x;
  const int xcd = bid & 7;
  const int idx = bid >> 3;
  const int w   = idx & 31;
  const int br  = (idx >> 5) * 8 + (w & 7);
  const int bc  = xcd * 4 + (w >> 3);

  // hoisted per-lane stage-source offsets (pre-swizzled)
  const int Pl0 = tid * 16;
  const int L0  = Pl0 ^ (((Pl0 >> 7) & 7) << 4);
  const int Pl1 = 8192 + tid * 16;
  const int L1  = Pl1 ^ (((Pl1 >> 7) & 7) << 4);
  const int g0  = (L0 >> 7) * 1024 + (L0 & 127);
  const int g1  = (L1 >> 7) * 1024 + (L1 & 127);
  const char* Ab = (const char*)Xnb + (size_t)br * 262144;  // 256 rows x 1KB
  const char* Bb = (const char*)Ynb + (size_t)bc * 262144;

  // hoisted swizzled LDS read bases
  const int aswz = (l16 & 7) << 4;
  const int raB[2] = { (wr * 128 + l16) * 128 + ((lg * 16)      ^ aswz),
                       (wr * 128 + l16) * 128 + ((lg * 16 + 64) ^ aswz) };
  const int rbB[2] = { 32768 + (wc * 64 + l16) * 128 + ((lg * 16)      ^ aswz),
                       32768 + (wc * 64 + l16) * 128 + ((lg * 16 + 64) ^ aswz) };

  f32x4  acc[8][4] = {};
  bf16x8 a0[2][4], a1[2][4];     // A frags, m-half 0 / 1  [kslice][i]
  bf16x8 b01[2][2], b23[2][2];   // B frags, cols 0-1 / 2-3 [kslice][j]

  // prologue: stage t0->buf0 and t1->buf1 (16 loads), wait t0 (vmcnt(8)),
  // then read t0's Q(0,0) operands.
  STAGE_A(0, 0);
  STAGE_B(0, 0);
  STAGE_A((1 << 16), 1);
  STAGE_B((1 << 16), 1);
  asm volatile("s_waitcnt vmcnt(8)" ::: "memory");
  __builtin_amdgcn_s_barrier();
  __builtin_amdgcn_sched_barrier(0);
  READ_A8(a0, 0, 0);
  READ_B4(b01, 0, 0);

#pragma unroll
  for (int t = 0; t < 8; ++t) {               // K = 512 = 8 x BK(64)
    const int cur   = (t & 1) << 16;
    const int other = cur ^ (1 << 16);
    // ---- Ph0 ----
    READ_A8(a1, cur, 1);
    QUADX(0, 0, a0, b01);
    PHASE_END_LGKM();
    // ---- Ph1 ----
    READ_B4(b23, cur, 2);
    if (t < 6) STAGE_A(cur, t + 2);
    QUADX(1, 0, a1, b01);
    asm volatile("s_waitcnt lgkmcnt(0)" ::: "memory");
    if (t < 6)       asm volatile("s_waitcnt vmcnt(4)" ::: "memory");
    else if (t == 6) asm volatile("s_waitcnt vmcnt(0)" ::: "memory");
    __builtin_amdgcn_s_barrier();
    __builtin_amdgcn_sched_barrier(0);
    // ---- Ph2 ----
    if (t < 7) READ_B4(b01, other, 0);        // next tile's B cols 0-1
    if (t < 6) STAGE_B(cur, t + 2);
    QUADX(0, 1, a0, b23);
    PHASE_END_LGKM();
    // ---- Ph3 ----
    QUADX(1, 1, a1, b23);
    if (t < 7) READ_A8(a0, other, 0);         // next tile's A m-half 0
    PHASE_END_LGKM();
  }

  // ---- epilogue: E = exp2(S*it - it); row/col partial sums (reuse sT) ----
  __syncthreads();
  float* rp = (float*)sT;            // [4][256]
  float* cp = (float*)(sT + 4096);   // [2][256]
  // D frag layout (m89): col = l16, row = lg*4 + reg within each 16x16
  float cacc[4] = {0.f, 0.f, 0.f, 0.f};
#pragma unroll
  for (int I = 0; I < 8; ++I) {
    float racc[4] = {0.f, 0.f, 0.f, 0.f};
#pragma unroll
    for (int J = 0; J < 4; ++J)
#pragma unroll
      for (int r = 0; r < 4; ++r) {
        const float e = exp2f(fmaf(acc[I][J][r], INV_T, -INV_T));
        racc[r] += e;
        cacc[J] += e;
      }
#pragma unroll
    for (int r = 0; r < 4; ++r) {
      float v = racc[r];
      v += __shfl_xor(v, 1); v += __shfl_xor(v, 2);
      v += __shfl_xor(v, 4); v += __shfl_xor(v, 8);
      if (l16 == 0) rp[wc * 256 + wr * 128 + I * 16 + lg * 4 + r] = v;
    }
  }
#pragma unroll
  for (int J = 0; J < 4; ++J) {
    float v = cacc[J];
    v += __shfl_xor(v, 16); v += __shfl_xor(v, 32);
    if (lg == 0) cp[wr * 256 + wc * 64 + J * 16 + l16] = v;
  }
  __syncthreads();
  if (tid < 256) {
    rowp[(size_t)bc * NB + br * 256 + tid] =
        rp[tid] + rp[256 + tid] + rp[512 + tid] + rp[768 + tid];
  } else {
    const int c = tid - 256;
    colp[(size_t)br * NB + bc * 256 + c] = cp[c] + cp[256 + c];
  }
}

// -------- kernel 3: reduce 32 partials per row/col, compute loss --------
__global__ __launch_bounds__(128) void loss_kernel(
    const float* __restrict__ rowp, const float* __restrict__ colp,
    const float* __restrict__ Sv, float* __restrict__ out) {
  __shared__ float wsum[2];
  const int i = blockIdx.x * 128 + threadIdx.x;   // 64 blocks x 128 thr
  float rs = 0.f, cs = 0.f;
#pragma unroll 4
  for (int b = 0; b < 32; ++b) {
    rs += rowp[(size_t)b * NB + i];
    cs += colp[(size_t)b * NB + i];
  }
  float v = 2.f * Sv[i] - logf(rs) - logf(cs);
#pragma unroll
  for (int m = 1; m < 64; m <<= 1) v += __shfl_xor(v, m);
  if ((threadIdx.x & 63) == 0) wsum[threadIdx.x >> 6] = v;
  __syncthreads();
  if (threadIdx.x == 0) {
    atomicAdd(out, (wsum[0] + wsum[1]) * (-1.0f / (2.0f * NB)));
  }
}

extern "C" void kernel_launch(void* const* d_in, const int* in_sizes, int n_in,
                              void* d_out, int out_size, void* d_ws, size_t ws_size,
                              hipStream_t stream) {
  const float* X = (const float*)d_in[0];   // image_features
  const float* Y = (const float*)d_in[1];   // text_features
  char* ws = (char*)d_ws;
  // workspace layout (~19 MB)
  unsigned short* Xnb = (unsigned short*)(ws);                       // 8 MB
  unsigned short* Ynb = (unsigned short*)(ws + 8388608);             // 8 MB
  float* Sv   = (float*)(ws + 16777216);                             // 32 KB
  float* rowp = (float*)(ws + 16777216 + 32768);                     // 1 MB
  float* colp = (float*)(ws + 16777216 + 32768 + 1048576);           // 1 MB
  float* out  = (float*)d_out;

  (void)hipFuncSetAttribute((const void*)gemm_kernel,
                            hipFuncAttributeMaxDynamicSharedMemorySize,
                            131072);

  hipMemsetAsync(d_out, 0, sizeof(float), stream);
  norm_kernel2<<<NB / 4, 256, 0, stream>>>(X, Y, Xnb, Ynb, Sv);
  gemm_kernel<<<1024, 512, 131072, stream>>>(Xnb, Ynb, rowp, colp);
  loss_kernel<<<64, 128, 0, stream>>>(rowp, colp, Sv, out);
}